// Round 9
// baseline (264.449 us; speedup 1.0000x reference)
//
#include <hip/hip_runtime.h>
#include <hip/hip_fp16.h>

static constexpr int Hh = 384;
static constexpr int Ww = 1280;
static constexpr int HW = Hh * Ww;            // 491520
static constexpr int NPIX = 2 * HW;           // 983040
static constexpr int TILE = 32;               // output tile side
static constexpr int S = 8;                   // fused Jacobi steps per launch
static constexpr int R = TILE + 2 * S;        // 48 region side
static constexpr int LBUF = 2404;             // (r+1)*48+c+1, r,c in [-1,48] -> max 2401
static constexpr int BLOCK = 256;             // 16x16 threads, 3x3 px each
static constexpr int TI = Hh / TILE;          // 12
static constexpr int TJ = Ww / TILE;          // 40
static constexpr int GRID = 2 * TI * TJ;      // 960 tiles
static constexpr float EPSF = 1e-9f;

// k order matches reference PADS: (di,dj) =
// k:   0       1       2       3       4       5       6       7
//    (+1,+1) (+1,0) (+1,-1) (0,+1) (0,-1) (-1,+1) (-1,0) (-1,-1)

__device__ __forceinline__ void pack_wc(const float v[8], float a, float rawv,
                                        float sp, float4* wout, float* Cout) {
    float inv = 1.0f / a;
    float w0 = v[0]*inv, w1 = v[1]*inv, w2 = v[2]*inv, w3 = v[3]*inv;
    float w4 = v[4]*inv, w5 = v[5]*inv, w6 = v[6]*inv, w7 = v[7]*inv;
    float gs = w0 + w1 + w2 + w3 + w4 + w5 + w6 + w7;
    bool m = sp > 0.0f;                 // sparse >= 0 always; sign(s)==1 iff s>0
    *Cout = m ? rawv : (1.0f - gs) * rawv;
    if (m) { w0=w1=w2=w3=w4=w5=w6=w7=0.0f; }
    float4 w;
    w.x = __builtin_bit_cast(float, __floats2half2_rn(w0, w1));
    w.y = __builtin_bit_cast(float, __floats2half2_rn(w2, w3));
    w.z = __builtin_bit_cast(float, __floats2half2_rn(w4, w5));
    w.w = __builtin_bit_cast(float, __floats2half2_rn(w6, w7));
    *wout = w;
}

// 4 px/thread; interior fast path = per channel one ALIGNED float4 + one edge
// scalar (shift in registers).
__global__ void affinity_norm(const float* __restrict__ g,
                              const float* __restrict__ raw,
                              const float* __restrict__ sparse,
                              __half* __restrict__ wbuf,
                              float* __restrict__ cbuf) {
    const int DI[8] = { 1, 1, 1, 0, 0, -1, -1, -1 };
    const int DJ[8] = { 1, 0, -1, 1, -1, 1, 0, -1 };

    int t = blockIdx.x * blockDim.x + threadIdx.x;
    if (t >= NPIX / 4) return;
    int idx0 = t * 4;
    int b = idx0 / HW;
    int r = idx0 - b * HW;
    int i = r / Ww;
    int j0 = r - i * Ww;
    const float* gb = g + (size_t)b * 8 * HW;
    float4* wq = (float4*)wbuf;

    if (i >= 1 && i < Hh - 1 && j0 >= 4 && j0 <= Ww - 8) {
        float vv[4][8];
        float acc[4] = { EPSF, EPSF, EPSF, EPSF };
#pragma unroll
        for (int k = 0; k < 8; k++) {
            const float* rowp = gb + k * HW + (i + DI[k]) * Ww;
            float4 v = *(const float4*)(rowp + j0);
            float e0, e1, e2, e3;
            if (DJ[k] == 0)      { e0 = v.x; e1 = v.y; e2 = v.z; e3 = v.w; }
            else if (DJ[k] == 1) { float s = rowp[j0 + 4]; e0 = v.y; e1 = v.z; e2 = v.w; e3 = s; }
            else                 { float s = rowp[j0 - 1]; e0 = s;   e1 = v.x; e2 = v.y; e3 = v.z; }
            vv[0][k] = e0; vv[1][k] = e1; vv[2][k] = e2; vv[3][k] = e3;
            acc[0] += fabsf(e0); acc[1] += fabsf(e1);
            acc[2] += fabsf(e2); acc[3] += fabsf(e3);
        }
        float4 raw4 = *(const float4*)(raw + idx0);
        float4 sp4  = *(const float4*)(sparse + idx0);
        float4 w0, w1, w2, w3;
        float  c0, c1, c2, c3;
        pack_wc(vv[0], acc[0], raw4.x, sp4.x, &w0, &c0);
        pack_wc(vv[1], acc[1], raw4.y, sp4.y, &w1, &c1);
        pack_wc(vv[2], acc[2], raw4.z, sp4.z, &w2, &c2);
        pack_wc(vv[3], acc[3], raw4.w, sp4.w, &w3, &c3);
        wq[idx0]     = w0;
        wq[idx0 + 1] = w1;
        wq[idx0 + 2] = w2;
        wq[idx0 + 3] = w3;
        *(float4*)(cbuf + idx0) = make_float4(c0, c1, c2, c3);
    } else {
        for (int q = 0; q < 4; q++) {
            int idx = idx0 + q;
            int j = j0 + q;
            float v[8];
            float a = EPSF;
#pragma unroll
            for (int k = 0; k < 8; k++) {
                int ii = i + DI[k], jj = j + DJ[k];
                float gv = 0.0f;
                if (ii >= 0 && ii < Hh && jj >= 0 && jj < Ww)
                    gv = gb[k * HW + ii * Ww + jj];
                v[k] = gv;
                a += fabsf(gv);
            }
            float4 w; float c;
            pack_wc(v, a, raw[idx], sparse[idx], &w, &c);
            wq[idx] = w;
            cbuf[idx] = c;
        }
    }
}

// LDS address for region px (r,c), r,c in [-1,48]. Wrap-aliased guard ring:
// aliased words only ever feed ring px (w==0) and are always finite.
__device__ __forceinline__ int LA(int r, int c) { return (r + 1) * R + c + 1; }

// Fused S=8 Jacobi steps, 48x48 region (32x32 valid center, halo 8).
// 16x16 threads x 3x3 px each. Patch d + weights + C in REGISTERS for all
// steps; per step only the 16-px halo is read from LDS and the 8 border px
// published. Lane stride 3 dwords, thread-row stride 144 ≡ 16 mod 32 ->
// exactly 2 lanes/bank (conflict-free). Ring/OOB px: w=0, C=d0 -> copy
// forward branchlessly.
__global__ __launch_bounds__(BLOCK, 4) void fused_steps(
    const __half* __restrict__ wbuf, const float* __restrict__ cbuf,
    const float* __restrict__ din, float* __restrict__ dout)
{
    __shared__ float sd[2][LBUF];

    const int tid = threadIdx.x;
    const int tc = tid & 15;
    const int tr = tid >> 4;
    int bx = blockIdx.x;
    const int tj = bx % TJ; bx /= TJ;
    const int ti = bx % TI;
    const int b  = bx / TI;
    const int oi = ti * TILE - S;
    const int oj = tj * TILE - S;
    const int r0 = 3 * tr;
    const int c0 = 3 * tc;

    for (int p = tid; p < LBUF; p += BLOCK) { sd[0][p] = 0.0f; sd[1][p] = 0.0f; }

    float d[3][3], C[3][3];
    __half2 w01[3][3], w23[3][3], w45[3][3], w67[3][3];

#pragma unroll
    for (int dr = 0; dr < 3; dr++) {
#pragma unroll
        for (int dc = 0; dc < 3; dc++) {
            const int rr = r0 + dr, cc = c0 + dc;
            const int gi = oi + rr, gj = oj + cc;
            const int gic = min(max(gi, 0), Hh - 1);
            const int gjc = min(max(gj, 0), Ww - 1);
            const int idx = b * HW + gic * Ww + gjc;
            const float dv = din[idx];
            const bool ring = (rr == 0) | (rr == R - 1) | (cc == 0) | (cc == R - 1)
                            | (gi != gic) | (gj != gjc);
            float4 w = make_float4(0.f, 0.f, 0.f, 0.f);
            float  c = dv;
            if (!ring) { w = ((const float4*)wbuf)[idx]; c = cbuf[idx]; }
            d[dr][dc] = dv;
            C[dr][dc] = c;
            w01[dr][dc] = __builtin_bit_cast(__half2, w.x);
            w23[dr][dc] = __builtin_bit_cast(__half2, w.y);
            w45[dr][dc] = __builtin_bit_cast(__half2, w.z);
            w67[dr][dc] = __builtin_bit_cast(__half2, w.w);
        }
    }
    __syncthreads();                     // zero-fill complete

    // publish initial borders (center (1,1) is never read by any neighbor)
    {
        float* s1 = sd[0];
        s1[LA(r0,     c0)]     = d[0][0];
        s1[LA(r0,     c0 + 1)] = d[0][1];
        s1[LA(r0,     c0 + 2)] = d[0][2];
        s1[LA(r0 + 1, c0)]     = d[1][0];
        s1[LA(r0 + 1, c0 + 2)] = d[1][2];
        s1[LA(r0 + 2, c0)]     = d[2][0];
        s1[LA(r0 + 2, c0 + 1)] = d[2][1];
        s1[LA(r0 + 2, c0 + 2)] = d[2][2];
    }
    __syncthreads();

    int cur = 0;
    for (int s = 1; s <= S; s++) {
        const float* s0 = sd[cur];
        // 16-px halo -> 5x5 window V (interior = registers)
        float V[5][5];
#pragma unroll
        for (int i = 0; i < 5; i++) V[0][i] = s0[LA(r0 - 1, c0 - 1 + i)];
#pragma unroll
        for (int i = 0; i < 5; i++) V[4][i] = s0[LA(r0 + 3, c0 - 1 + i)];
#pragma unroll
        for (int i = 0; i < 3; i++) V[1 + i][0] = s0[LA(r0 + i, c0 - 1)];
#pragma unroll
        for (int i = 0; i < 3; i++) V[1 + i][4] = s0[LA(r0 + i, c0 + 3)];
#pragma unroll
        for (int dr = 0; dr < 3; dr++)
#pragma unroll
            for (int dc = 0; dc < 3; dc++) V[1 + dr][1 + dc] = d[dr][dc];

        float nd[3][3];
#pragma unroll
        for (int dr = 0; dr < 3; dr++) {
#pragma unroll
            for (int dc = 0; dc < 3; dc++) {
                nd[dr][dc] = C[dr][dc]
                    + __half2float(w01[dr][dc].x) * V[dr + 2][dc + 2]
                    + __half2float(w01[dr][dc].y) * V[dr + 2][dc + 1]
                    + __half2float(w23[dr][dc].x) * V[dr + 2][dc]
                    + __half2float(w23[dr][dc].y) * V[dr + 1][dc + 2]
                    + __half2float(w45[dr][dc].x) * V[dr + 1][dc]
                    + __half2float(w45[dr][dc].y) * V[dr][dc + 2]
                    + __half2float(w67[dr][dc].x) * V[dr][dc + 1]
                    + __half2float(w67[dr][dc].y) * V[dr][dc];
            }
        }
#pragma unroll
        for (int dr = 0; dr < 3; dr++)
#pragma unroll
            for (int dc = 0; dc < 3; dc++) d[dr][dc] = nd[dr][dc];

        if (s < S) {
            float* s1 = sd[cur ^ 1];
            s1[LA(r0,     c0)]     = d[0][0];
            s1[LA(r0,     c0 + 1)] = d[0][1];
            s1[LA(r0,     c0 + 2)] = d[0][2];
            s1[LA(r0 + 1, c0)]     = d[1][0];
            s1[LA(r0 + 1, c0 + 2)] = d[1][2];
            s1[LA(r0 + 2, c0)]     = d[2][0];
            s1[LA(r0 + 2, c0 + 1)] = d[2][1];
            s1[LA(r0 + 2, c0 + 2)] = d[2][2];
            __syncthreads();
            cur ^= 1;
        }
    }

    // store valid 32x32 center
#pragma unroll
    for (int dr = 0; dr < 3; dr++) {
#pragma unroll
        for (int dc = 0; dc < 3; dc++) {
            const int rr = r0 + dr, cc = c0 + dc;
            if (rr >= S && rr < R - S && cc >= S && cc < R - S)
                dout[b * HW + (oi + rr) * Ww + (oj + cc)] = d[dr][dc];
        }
    }
}

extern "C" void kernel_launch(void* const* d_in, const int* in_sizes, int n_in,
                              void* d_out, int out_size, void* d_ws, size_t ws_size,
                              hipStream_t stream) {
    const float* guidance = (const float*)d_in[0];
    const float* blur     = (const float*)d_in[1];
    const float* sparse   = (const float*)d_in[2];
    float* out = (float*)d_out;

    char* ws = (char*)d_ws;
    float* bufA = (float*)ws;
    float* bufB = bufA + NPIX;
    __half* wbuf = (__half*)(bufB + NPIX);          // NPIX*8 fp16 = 15.7 MB
    float*  cbuf = (float*)(wbuf + (size_t)NPIX * 8);

    affinity_norm<<<NPIX / 4 / 256, 256, 0, stream>>>(guidance, blur, sparse, wbuf, cbuf);

    // 24 steps = 3 launches x 8 fused steps
    fused_steps<<<GRID, BLOCK, 0, stream>>>(wbuf, cbuf, blur, bufA);
    fused_steps<<<GRID, BLOCK, 0, stream>>>(wbuf, cbuf, bufA, bufB);
    fused_steps<<<GRID, BLOCK, 0, stream>>>(wbuf, cbuf, bufB, out);
}

// Round 10
// 217.591 us; speedup vs baseline: 1.2154x; 1.2154x over previous
//
#include <hip/hip_runtime.h>
#include <hip/hip_fp16.h>

static constexpr int Hh = 384;
static constexpr int Ww = 1280;
static constexpr int HW = Hh * Ww;            // 491520
static constexpr int NPIX = 2 * HW;           // 983040
static constexpr int TILE = 32;               // output tile side
static constexpr int S = 8;                   // fused Jacobi steps per launch
static constexpr int R = TILE + 2 * S;        // 48 region side
static constexpr int LBUF = 2404;             // (r+1)*48+c+1, r,c in [-1,48] -> max 2401
static constexpr int BLOCK = 256;             // 16x16 threads, 3x3 px each
static constexpr int TI = Hh / TILE;          // 12
static constexpr int TJ = Ww / TILE;          // 40
static constexpr int GRID = 2 * TI * TJ;      // 960 tiles
static constexpr float EPSF = 1e-9f;

// k order matches reference PADS: (di,dj) =
// k:   0       1       2       3       4       5       6       7
//    (+1,+1) (+1,0) (+1,-1) (0,+1) (0,-1) (-1,+1) (-1,0) (-1,-1)

__device__ __forceinline__ void pack_wc(const float v[8], float a, float rawv,
                                        float sp, float4* wout, float* Cout) {
    float inv = 1.0f / a;
    float w0 = v[0]*inv, w1 = v[1]*inv, w2 = v[2]*inv, w3 = v[3]*inv;
    float w4 = v[4]*inv, w5 = v[5]*inv, w6 = v[6]*inv, w7 = v[7]*inv;
    float gs = w0 + w1 + w2 + w3 + w4 + w5 + w6 + w7;
    bool m = sp > 0.0f;                 // sparse >= 0 always; sign(s)==1 iff s>0
    *Cout = m ? rawv : (1.0f - gs) * rawv;
    if (m) { w0=w1=w2=w3=w4=w5=w6=w7=0.0f; }
    float4 w;
    w.x = __builtin_bit_cast(float, __floats2half2_rn(w0, w1));
    w.y = __builtin_bit_cast(float, __floats2half2_rn(w2, w3));
    w.z = __builtin_bit_cast(float, __floats2half2_rn(w4, w5));
    w.w = __builtin_bit_cast(float, __floats2half2_rn(w6, w7));
    *wout = w;
}

// 4 px/thread; interior fast path = per channel one ALIGNED float4 + one edge
// scalar (shift in registers).
__global__ void affinity_norm(const float* __restrict__ g,
                              const float* __restrict__ raw,
                              const float* __restrict__ sparse,
                              __half* __restrict__ wbuf,
                              float* __restrict__ cbuf) {
    const int DI[8] = { 1, 1, 1, 0, 0, -1, -1, -1 };
    const int DJ[8] = { 1, 0, -1, 1, -1, 1, 0, -1 };

    int t = blockIdx.x * blockDim.x + threadIdx.x;
    if (t >= NPIX / 4) return;
    int idx0 = t * 4;
    int b = idx0 / HW;
    int r = idx0 - b * HW;
    int i = r / Ww;
    int j0 = r - i * Ww;
    const float* gb = g + (size_t)b * 8 * HW;
    float4* wq = (float4*)wbuf;

    if (i >= 1 && i < Hh - 1 && j0 >= 4 && j0 <= Ww - 8) {
        float vv[4][8];
        float acc[4] = { EPSF, EPSF, EPSF, EPSF };
#pragma unroll
        for (int k = 0; k < 8; k++) {
            const float* rowp = gb + k * HW + (i + DI[k]) * Ww;
            float4 v = *(const float4*)(rowp + j0);
            float e0, e1, e2, e3;
            if (DJ[k] == 0)      { e0 = v.x; e1 = v.y; e2 = v.z; e3 = v.w; }
            else if (DJ[k] == 1) { float s = rowp[j0 + 4]; e0 = v.y; e1 = v.z; e2 = v.w; e3 = s; }
            else                 { float s = rowp[j0 - 1]; e0 = s;   e1 = v.x; e2 = v.y; e3 = v.z; }
            vv[0][k] = e0; vv[1][k] = e1; vv[2][k] = e2; vv[3][k] = e3;
            acc[0] += fabsf(e0); acc[1] += fabsf(e1);
            acc[2] += fabsf(e2); acc[3] += fabsf(e3);
        }
        float4 raw4 = *(const float4*)(raw + idx0);
        float4 sp4  = *(const float4*)(sparse + idx0);
        float4 w0, w1, w2, w3;
        float  c0, c1, c2, c3;
        pack_wc(vv[0], acc[0], raw4.x, sp4.x, &w0, &c0);
        pack_wc(vv[1], acc[1], raw4.y, sp4.y, &w1, &c1);
        pack_wc(vv[2], acc[2], raw4.z, sp4.z, &w2, &c2);
        pack_wc(vv[3], acc[3], raw4.w, sp4.w, &w3, &c3);
        wq[idx0]     = w0;
        wq[idx0 + 1] = w1;
        wq[idx0 + 2] = w2;
        wq[idx0 + 3] = w3;
        *(float4*)(cbuf + idx0) = make_float4(c0, c1, c2, c3);
    } else {
        for (int q = 0; q < 4; q++) {
            int idx = idx0 + q;
            int j = j0 + q;
            float v[8];
            float a = EPSF;
#pragma unroll
            for (int k = 0; k < 8; k++) {
                int ii = i + DI[k], jj = j + DJ[k];
                float gv = 0.0f;
                if (ii >= 0 && ii < Hh && jj >= 0 && jj < Ww)
                    gv = gb[k * HW + ii * Ww + jj];
                v[k] = gv;
                a += fabsf(gv);
            }
            float4 w; float c;
            pack_wc(v, a, raw[idx], sparse[idx], &w, &c);
            wq[idx] = w;
            cbuf[idx] = c;
        }
    }
}

// LDS address for region px (r,c), r,c in [-1,48]. Wrap-aliased guard ring:
// aliased words only ever feed ring px (w==0) and are always finite.
__device__ __forceinline__ int LA(int r, int c) { return (r + 1) * R + c + 1; }

// Fused S=8 Jacobi steps, 48x48 region (32x32 valid center, halo 8).
// 16x16 threads x 3x3 px each. Patch d + weights + C in REGISTERS for all
// steps (needs ~115 VGPRs: launch_bounds min-waves=2 caps at 256 so the
// allocator does NOT spill — r9's (,4) forced a 64-reg allocation and 52.8 MB
// of scratch writes). Per step only the 16-px halo is read from LDS and the
// 8 border px published. Lane stride 3 dwords, thread-row stride 144 ≡ 16
// mod 32 -> exactly 2 lanes/bank (measured 0 conflicts in r9). Ring/OOB px:
// w=0, C=d0 -> copy forward branchlessly.
__global__ __launch_bounds__(BLOCK, 2) void fused_steps(
    const __half* __restrict__ wbuf, const float* __restrict__ cbuf,
    const float* __restrict__ din, float* __restrict__ dout)
{
    __shared__ float sd[2][LBUF];

    const int tid = threadIdx.x;
    const int tc = tid & 15;
    const int tr = tid >> 4;
    int bx = blockIdx.x;
    const int tj = bx % TJ; bx /= TJ;
    const int ti = bx % TI;
    const int b  = bx / TI;
    const int oi = ti * TILE - S;
    const int oj = tj * TILE - S;
    const int r0 = 3 * tr;
    const int c0 = 3 * tc;

    for (int p = tid; p < LBUF; p += BLOCK) { sd[0][p] = 0.0f; sd[1][p] = 0.0f; }

    float d[3][3], C[3][3];
    __half2 w01[3][3], w23[3][3], w45[3][3], w67[3][3];

#pragma unroll
    for (int dr = 0; dr < 3; dr++) {
#pragma unroll
        for (int dc = 0; dc < 3; dc++) {
            const int rr = r0 + dr, cc = c0 + dc;
            const int gi = oi + rr, gj = oj + cc;
            const int gic = min(max(gi, 0), Hh - 1);
            const int gjc = min(max(gj, 0), Ww - 1);
            const int idx = b * HW + gic * Ww + gjc;
            const float dv = din[idx];
            const bool ring = (rr == 0) | (rr == R - 1) | (cc == 0) | (cc == R - 1)
                            | (gi != gic) | (gj != gjc);
            float4 w = make_float4(0.f, 0.f, 0.f, 0.f);
            float  c = dv;
            if (!ring) { w = ((const float4*)wbuf)[idx]; c = cbuf[idx]; }
            d[dr][dc] = dv;
            C[dr][dc] = c;
            w01[dr][dc] = __builtin_bit_cast(__half2, w.x);
            w23[dr][dc] = __builtin_bit_cast(__half2, w.y);
            w45[dr][dc] = __builtin_bit_cast(__half2, w.z);
            w67[dr][dc] = __builtin_bit_cast(__half2, w.w);
        }
    }
    __syncthreads();                     // zero-fill complete

    // publish initial borders (center (1,1) is never read by any neighbor)
    {
        float* s1 = sd[0];
        s1[LA(r0,     c0)]     = d[0][0];
        s1[LA(r0,     c0 + 1)] = d[0][1];
        s1[LA(r0,     c0 + 2)] = d[0][2];
        s1[LA(r0 + 1, c0)]     = d[1][0];
        s1[LA(r0 + 1, c0 + 2)] = d[1][2];
        s1[LA(r0 + 2, c0)]     = d[2][0];
        s1[LA(r0 + 2, c0 + 1)] = d[2][1];
        s1[LA(r0 + 2, c0 + 2)] = d[2][2];
    }
    __syncthreads();

    int cur = 0;
    for (int s = 1; s <= S; s++) {
        const float* s0 = sd[cur];
        // 16-px halo -> 5x5 window V (interior = registers)
        float V[5][5];
#pragma unroll
        for (int i = 0; i < 5; i++) V[0][i] = s0[LA(r0 - 1, c0 - 1 + i)];
#pragma unroll
        for (int i = 0; i < 5; i++) V[4][i] = s0[LA(r0 + 3, c0 - 1 + i)];
#pragma unroll
        for (int i = 0; i < 3; i++) V[1 + i][0] = s0[LA(r0 + i, c0 - 1)];
#pragma unroll
        for (int i = 0; i < 3; i++) V[1 + i][4] = s0[LA(r0 + i, c0 + 3)];
#pragma unroll
        for (int dr = 0; dr < 3; dr++)
#pragma unroll
            for (int dc = 0; dc < 3; dc++) V[1 + dr][1 + dc] = d[dr][dc];

        float nd[3][3];
#pragma unroll
        for (int dr = 0; dr < 3; dr++) {
#pragma unroll
            for (int dc = 0; dc < 3; dc++) {
                nd[dr][dc] = C[dr][dc]
                    + __half2float(w01[dr][dc].x) * V[dr + 2][dc + 2]
                    + __half2float(w01[dr][dc].y) * V[dr + 2][dc + 1]
                    + __half2float(w23[dr][dc].x) * V[dr + 2][dc]
                    + __half2float(w23[dr][dc].y) * V[dr + 1][dc + 2]
                    + __half2float(w45[dr][dc].x) * V[dr + 1][dc]
                    + __half2float(w45[dr][dc].y) * V[dr][dc + 2]
                    + __half2float(w67[dr][dc].x) * V[dr][dc + 1]
                    + __half2float(w67[dr][dc].y) * V[dr][dc];
            }
        }
#pragma unroll
        for (int dr = 0; dr < 3; dr++)
#pragma unroll
            for (int dc = 0; dc < 3; dc++) d[dr][dc] = nd[dr][dc];

        if (s < S) {
            float* s1 = sd[cur ^ 1];
            s1[LA(r0,     c0)]     = d[0][0];
            s1[LA(r0,     c0 + 1)] = d[0][1];
            s1[LA(r0,     c0 + 2)] = d[0][2];
            s1[LA(r0 + 1, c0)]     = d[1][0];
            s1[LA(r0 + 1, c0 + 2)] = d[1][2];
            s1[LA(r0 + 2, c0)]     = d[2][0];
            s1[LA(r0 + 2, c0 + 1)] = d[2][1];
            s1[LA(r0 + 2, c0 + 2)] = d[2][2];
            __syncthreads();
            cur ^= 1;
        }
    }

    // store valid 32x32 center
#pragma unroll
    for (int dr = 0; dr < 3; dr++) {
#pragma unroll
        for (int dc = 0; dc < 3; dc++) {
            const int rr = r0 + dr, cc = c0 + dc;
            if (rr >= S && rr < R - S && cc >= S && cc < R - S)
                dout[b * HW + (oi + rr) * Ww + (oj + cc)] = d[dr][dc];
        }
    }
}

extern "C" void kernel_launch(void* const* d_in, const int* in_sizes, int n_in,
                              void* d_out, int out_size, void* d_ws, size_t ws_size,
                              hipStream_t stream) {
    const float* guidance = (const float*)d_in[0];
    const float* blur     = (const float*)d_in[1];
    const float* sparse   = (const float*)d_in[2];
    float* out = (float*)d_out;

    char* ws = (char*)d_ws;
    float* bufA = (float*)ws;
    float* bufB = bufA + NPIX;
    __half* wbuf = (__half*)(bufB + NPIX);          // NPIX*8 fp16 = 15.7 MB
    float*  cbuf = (float*)(wbuf + (size_t)NPIX * 8);

    affinity_norm<<<NPIX / 4 / 256, 256, 0, stream>>>(guidance, blur, sparse, wbuf, cbuf);

    // 24 steps = 3 launches x 8 fused steps
    fused_steps<<<GRID, BLOCK, 0, stream>>>(wbuf, cbuf, blur, bufA);
    fused_steps<<<GRID, BLOCK, 0, stream>>>(wbuf, cbuf, bufA, bufB);
    fused_steps<<<GRID, BLOCK, 0, stream>>>(wbuf, cbuf, bufB, out);
}